// Round 2
// baseline (158.911 us; speedup 1.0000x reference)
//
#include <hip/hip_runtime.h>

typedef unsigned short u16;
typedef unsigned int u32;
typedef __attribute__((ext_vector_type(8))) short s16x8;   // 8 bf16 (4 VGPR) MFMA A/B frag
typedef __attribute__((ext_vector_type(4))) float f32x4;   // MFMA C/D frag

// Problem dims: B=4, X=32, H=8, W=128, C=32 (all fp32 in/out)
// Attention view: 4096 keys, M=256 cols, 128 distinct query rows per batch.
//
// r11: conv rewritten o-outer/j-inner so weight reads are a single linear
//   s_load stream (96 x dwordx16 per wave, was 1536 x dword stride-384 in
//   r10 -> 81% stall, 55us). vf[c*3+dx] input re-layout, scalar acc,
//   boundary taps as zeros (fmaf(0,w,a)=a, bit-exact). Everything else
//   from r10 kept: 3 launches, qproj folded into flash, LDS-transpose
//   coalesced K/V stores.
// ws layout:
//  WS_A:  Opart fp32 [64][128][256] = 8 MB  [0, 8388608)
//  WS_B:  K bf16 [4][4096][256]     = 8 MB  [8388608, 16777216)
//  WS_C:  V bf16 [4][4096][256]     = 8 MB  [16777216, 25165824)
//  WS_LP: lpart fp32 [64][128]      = 32KB  [25452544, 25485312)
#define WS_A      0u
#define WS_B      8388608u
#define WS_C      16777216u
#define WS_LP     25452544u
#define WS_NEEDED 25485312u

__device__ __forceinline__ u16 f2bf(float f){
  u32 u = __float_as_uint(f);
  return (u16)((u + 0x7fffu + ((u >> 16) & 1u)) >> 16);   // RNE
}

__global__ __launch_bounds__(256) void zero_out_kernel(float* __restrict__ out){
  int t = blockIdx.x * 256 + threadIdx.x;
  ((float4*)out)[t] = make_float4(0.f, 0.f, 0.f, 0.f);
}

// K0: Conv3d(32->64ch, k=(3,1,1), pad=(1,0,0)). 16 channels per block.
// Block = (b, x, wc, og2). o-outer / j-inner: for each output channel o the
// 96 weights w_cross[o*96 + (c*3+dx)] are CONTIGUOUS -> compiler emits
// s_load_dwordx16 batches and pipelines the linear 6KB stream across the
// 96-FMA bodies. Inputs pre-scattered to vf[c*3+dx] (96 VGPR, compile-time
// indexed); OOB x-taps are vf=0 (fmaf(0,w,a)=a, bit-exact vs skip).
// Epilogue: LDS transpose [16ch][256m] -> 2 coalesced uint4 stores/thread.
__global__ __launch_bounds__(256, 2) void conv_kernel(const float* __restrict__ storage,
    const float* __restrict__ w_cross, const float* __restrict__ b_cross,
    u16* __restrict__ Kb, u16* __restrict__ Vb){
  int bid = blockIdx.x;
  int wc  = bid & 3;
  int x   = (bid >> 2) & 31;
  int og2 = (bid >> 7) & 3;
  int b   = bid >> 9;
  int tid = threadIdx.x;
  int wl = tid & 31, h = tid >> 5;
  int w = wc * 32 + wl;
  int obase_ch = og2 * 16;

  // input re-layout: vf[c*3+dx], zeros for OOB taps
  float vf[96];
  #pragma unroll
  for (int dx = 0; dx < 3; ++dx){
    int xx = x + dx - 1;
    if (xx < 0 || xx > 31){              // block-uniform
      #pragma unroll
      for (int c = 0; c < 32; ++c) vf[c*3 + dx] = 0.f;
    } else {
      const float4* p = (const float4*)(storage + ((((size_t)b*32 + xx)*8 + h)*128 + w)*32);
      #pragma unroll
      for (int q = 0; q < 8; ++q){
        float4 v = p[q];
        vf[(q*4+0)*3 + dx] = v.x; vf[(q*4+1)*3 + dx] = v.y;
        vf[(q*4+2)*3 + dx] = v.z; vf[(q*4+3)*3 + dx] = v.w;
      }
    }
  }

  __shared__ u16 st[16*256];
  int m = wl*8 + h;
  const float* wbase = w_cross + (size_t)obase_ch * 96;   // 6KB linear slab
  #pragma unroll
  for (int o = 0; o < 16; ++o){
    float a = b_cross[obase_ch + o];
    #pragma unroll
    for (int j = 0; j < 96; ++j) a = fmaf(vf[j], wbase[o*96 + j], a);
    st[o*256 + m] = f2bf(a);
  }
  __syncthreads();

  // coalesced store: thread t -> ch = t>>4, m16 = (t&15)*16
  int ch = tid >> 4, m16 = (tid & 15) * 16;
  int ck = obase_ch + ch - (og2 >= 2 ? 32 : 0);
  size_t base = ((size_t)b*4096 + (size_t)x*4 + wc)*256 + (size_t)ck*32768 + m16;
  u16* dst = (og2 < 2 ? Vb : Kb) + base;
  *(uint4*)dst       = *(const uint4*)&st[ch*256 + m16];
  *(uint4*)(dst + 8) = *(const uint4*)&st[ch*256 + m16 + 8];
}

// K1: flash v2 + integrated qproj. Block = (b, kq: 16 x 256-key chunk,
// rb: 8 x 16-row). Grid 512. Prologue: each thread (wl,h) computes the 16
// Q values (cql x wcq) for its column m = wl*8+h — identical FMA order to
// the original prep kernel -> bit-identical bf16 Q. Staged in LDS (overlay
// on Vts, padded rows of 264 u16 so qa reads are 2-way/free), then qa frags.
// Main loop: no-max softmax, K direct-from-global, V^T LDS XOR-swizzled,
// kq-split sums.
__global__ __launch_bounds__(256, 2) void flash_kernel(const float* __restrict__ target,
    const float* __restrict__ w_q, const float* __restrict__ b_q,
    const u16* __restrict__ Kb, const u16* __restrict__ Vb,
    float* __restrict__ Opart, float* __restrict__ lpart){
  int kq = blockIdx.x & 15, rb = (blockIdx.x >> 4) & 7, b = blockIdx.x >> 7;
  int tid = threadIdx.x;
  int w = tid >> 6, lane = tid & 63, l15 = lane & 15, quad = lane >> 4;

  __shared__ alignas(16) u16 Vts[256 * 64];   // [m][64 keys] XOR-swizzled, 32KB
  __shared__ alignas(16) u16 Ps[16 * 64];     // [row][64 keys] XOR-swizzled, 2KB
  __shared__ float lsumW[64];                 // [wave][16 rows]

  // ---- integrated qproj: rows r_local = cql*4 + wcq (global cq = rb*4+cql) ----
  u16* stgQ = Vts;   // overlay: 16 rows x 264 u16 = 8448 B
  {
    int wl = tid & 31, h = tid >> 5;
    #pragma unroll
    for (int wcq = 0; wcq < 4; ++wcq){
      float in[32];
      const float4* p = (const float4*)(target + (((size_t)b*8 + h)*128 + wcq*32 + wl)*32);
      #pragma unroll
      for (int q = 0; q < 8; ++q){
        float4 v = p[q];
        in[q*4+0] = v.x; in[q*4+1] = v.y; in[q*4+2] = v.z; in[q*4+3] = v.w;
      }
      #pragma unroll
      for (int cql = 0; cql < 4; ++cql){
        int cq = rb*4 + cql;                       // block-uniform
        float acc = b_q[cq];
        #pragma unroll
        for (int c = 0; c < 32; ++c) acc = fmaf(in[c], w_q[cq*32 + c], acc);
        stgQ[(cql*4 + wcq)*264 + wl*8 + h] = f2bf(acc);
      }
    }
  }
  __syncthreads();

  // persistent Q A-frags: local rows l15, k = ks*32 + quad*8
  s16x8 qa[8];
  {
    const u16* qp = stgQ + l15*264 + quad*8;
    #pragma unroll
    for (int ks = 0; ks < 8; ++ks) qa[ks] = *(const s16x8*)(qp + ks*32);
  }
  __syncthreads();   // all qa reads done before Vts is reused

  int jl4 = tid & 15, mseg = tid >> 4;   // V staging: keys jl4*4..+3, m mseg*16..+15
  const u16* kbase = Kb + ((size_t)(b*4096 + kq*256 + w*16 + l15))*256 + quad*8;
  const u16* vbase = Vb + ((size_t)(b*4096 + kq*256 + jl4*4))*256 + mseg*16;

  // prefetch tile 0
  s16x8 kr[8];
  #pragma unroll
  for (int ks = 0; ks < 8; ++ks) kr[ks] = *(const s16x8*)(kbase + ks*32);
  u32 kv[4][8];
  #pragma unroll
  for (int kk = 0; kk < 4; ++kk){
    uint4 a = *(const uint4*)(vbase + kk*256);
    uint4 b2 = *(const uint4*)(vbase + kk*256 + 8);
    kv[kk][0]=a.x; kv[kk][1]=a.y; kv[kk][2]=a.z; kv[kk][3]=a.w;
    kv[kk][4]=b2.x; kv[kk][5]=b2.y; kv[kk][6]=b2.z; kv[kk][7]=b2.w;
  }

  float lacc[4] = {0.f, 0.f, 0.f, 0.f};
  f32x4 oc[4];
  #pragma unroll
  for (int mt = 0; mt < 4; ++mt) oc[mt] = (f32x4){0.f,0.f,0.f,0.f};

  #pragma unroll
  for (int it = 0; it < 4; ++it){
    if (it > 0) __syncthreads();   // prev PV done reading Vts/Ps

    // ---- phase 1: V^T -> LDS (b64 transposed, swizzled) ----
    #pragma unroll
    for (int i = 0; i < 16; ++i){
      int d = i >> 1;
      u32 e0, e1, e2, e3;
      if (i & 1){ e0 = kv[0][d] >> 16;     e1 = kv[1][d] >> 16;
                  e2 = kv[2][d] >> 16;     e3 = kv[3][d] >> 16; }
      else      { e0 = kv[0][d] & 0xffffu; e1 = kv[1][d] & 0xffffu;
                  e2 = kv[2][d] & 0xffffu; e3 = kv[3][d] & 0xffffu; }
      int m = mseg*16 + i;
      int col = (((jl4 >> 1) ^ (m & 7)) << 3) + ((jl4 & 1) << 2);
      *(uint2*)&Vts[m*64 + col] = make_uint2(e0 | (e1 << 16), e2 | (e3 << 16));
    }

    // ---- scores: D[row=quad*4+reg][key=w*16+l15], K frags from regs ----
    f32x4 s0 = {0.f,0.f,0.f,0.f}, s1 = {0.f,0.f,0.f,0.f};
    #pragma unroll
    for (int ks = 0; ks < 8; ks += 2){
      s0 = __builtin_amdgcn_mfma_f32_16x16x32_bf16(qa[ks],   kr[ks],   s0, 0, 0, 0);
      s1 = __builtin_amdgcn_mfma_f32_16x16x32_bf16(qa[ks+1], kr[ks+1], s1, 0, 0, 0);
    }
    int b8k = w*2 + (l15 >> 3);
    #pragma unroll
    for (int reg = 0; reg < 4; ++reg){
      float sv = fminf(s0[reg] + s1[reg], 80.f);
      float p = __expf(sv);
      int row = quad*4 + reg;
      Ps[row*64 + ((b8k ^ (row & 7)) << 3) + (l15 & 7)] = f2bf(p);
      lacc[reg] += p;
    }

    // prefetch V(t+1)
    if (it < 3){
      const u16* vp = vbase + (it+1)*16384;
      #pragma unroll
      for (int kk = 0; kk < 4; ++kk){
        uint4 a = *(const uint4*)(vp + kk*256);
        uint4 b2 = *(const uint4*)(vp + kk*256 + 8);
        kv[kk][0]=a.x; kv[kk][1]=a.y; kv[kk][2]=a.z; kv[kk][3]=a.w;
        kv[kk][4]=b2.x; kv[kk][5]=b2.y; kv[kk][6]=b2.z; kv[kk][7]=b2.w;
      }
    }
    __syncthreads();

    // ---- phase 2: PV. prefetch K(t+1) first (covered by MFMAs) ----
    if (it < 3){
      const u16* kp = kbase + (it+1)*16384;
      #pragma unroll
      for (int ks = 0; ks < 8; ++ks) kr[ks] = *(const s16x8*)(kp + ks*32);
    }
    #pragma unroll
    for (int ks2 = 0; ks2 < 2; ++ks2){
      int b8 = ks2*4 + quad;
      s16x8 pb = *(const s16x8*)&Ps[l15*64 + ((b8 ^ (l15 & 7)) << 3)];
      #pragma unroll
      for (int mt = 0; mt < 4; ++mt){
        int mrow = (w*4 + mt)*16 + l15;
        s16x8 af = *(const s16x8*)&Vts[mrow*64 + ((b8 ^ (mrow & 7)) << 3)];
        oc[mt] = __builtin_amdgcn_mfma_f32_16x16x32_bf16(af, pb, oc[mt], 0, 0, 0);
      }
    }
  }

  // ---- epilogue ----
  #pragma unroll
  for (int reg = 0; reg < 4; ++reg){
    float t = lacc[reg];
    t += __shfl_xor(t, 1); t += __shfl_xor(t, 2);
    t += __shfl_xor(t, 4); t += __shfl_xor(t, 8);
    lacc[reg] = t;
  }
  if (l15 == 0){
    #pragma unroll
    for (int reg = 0; reg < 4; ++reg) lsumW[w*16 + quad*4 + reg] = lacc[reg];
  }
  __syncthreads();
  if (tid < 16)
    lpart[(b*16 + kq)*128 + rb*16 + tid] =
        lsumW[tid] + lsumW[16 + tid] + lsumW[32 + tid] + lsumW[48 + tid];
  // O: lane holds rows l15, m = w*64 + mt*16 + quad*4 + reg
  {
    float* dst = Opart + ((size_t)((b*16 + kq)*128 + rb*16 + l15))*256 + w*64 + quad*4;
    #pragma unroll
    for (int mt = 0; mt < 4; ++mt)
      *(float4*)(dst + mt*16) = make_float4(oc[mt][0], oc[mt][1], oc[mt][2], oc[mt][3]);
  }
}

// K2: combine 16 kq-partials (plain sums — softmax un-normalized), divide,
// broadcast-scatter (row r=(cq,whi) -> 32 slots, contiguous 256-float stores).
__global__ __launch_bounds__(256) void combine_kernel(const float* __restrict__ lpart,
    const float* __restrict__ Opart, float* __restrict__ out){
  int r = blockIdx.x & 127, b = blockIdx.x >> 7;
  int m = threadIdx.x;
  float L = 0.f, o = 0.f;
  #pragma unroll
  for (int kq = 0; kq < 16; ++kq){
    L += lpart[(b*16 + kq)*128 + r];
    o += Opart[((size_t)((b*16 + kq)*128 + r))*256 + m];
  }
  o /= L;
  int cq = r >> 2, whi = r & 3;
  size_t obase = ((size_t)b*32 + cq) * 32768;
  #pragma unroll
  for (int hh = 0; hh < 8; ++hh){
    #pragma unroll
    for (int wt = 0; wt < 4; ++wt){
      out[obase + hh*4096 + wt*1024 + whi*256 + m] = o;
    }
  }
}

extern "C" void kernel_launch(void* const* d_in, const int* in_sizes, int n_in,
                              void* d_out, int out_size, void* d_ws, size_t ws_size,
                              hipStream_t stream){
  const float* storage = (const float*)d_in[0];
  const float* target  = (const float*)d_in[1];
  const float* w_cross = (const float*)d_in[2];
  const float* b_cross = (const float*)d_in[3];
  const float* w_q     = (const float*)d_in[4];
  const float* b_q     = (const float*)d_in[5];
  float* out = (float*)d_out;

  if (ws_size < (size_t)WS_NEEDED){
    zero_out_kernel<<<dim3(4096), dim3(256), 0, stream>>>(out);
    return;
  }

  char* ws = (char*)d_ws;
  float* Opart = (float*)(ws + WS_A);
  u16*   Kb    = (u16*)(ws + WS_B);
  u16*   Vb    = (u16*)(ws + WS_C);
  float* lpart = (float*)(ws + WS_LP);

  conv_kernel    <<<dim3(2048), dim3(256), 0, stream>>>(storage, w_cross, b_cross, Kb, Vb);
  flash_kernel   <<<dim3(512),  dim3(256), 0, stream>>>(target, w_q, b_q, Kb, Vb, Opart, lpart);
  combine_kernel <<<dim3(512),  dim3(256), 0, stream>>>(lpart, Opart, out);
}

// Round 3
// 143.428 us; speedup vs baseline: 1.1080x; 1.1080x over previous
//
#include <hip/hip_runtime.h>

typedef unsigned short u16;
typedef unsigned int u32;
typedef __attribute__((ext_vector_type(8))) short s16x8;   // 8 bf16 (4 VGPR) MFMA A/B frag
typedef __attribute__((ext_vector_type(4))) float f32x4;   // MFMA C/D frag

// Problem dims: B=4, X=32, H=8, W=128, C=32 (all fp32 in/out)
// Attention view: 4096 keys, M=256 cols, 128 distinct query rows per batch.
//
// r12: conv rewritten as MFMA GEMM with bf16 hi/lo split (fp32 emulation).
//   D[o=64][m] = sum_dx W_dx[64][32] . In_{x+dx-1}[32][m]; K=32 -> one
//   16x16x32 MFMA per (tile, dx) x 3 products (hihi + hilo + lohi;
//   lo.lo ~2^-14 skipped). c is innermost in storage -> B-frag = one 32B
//   contiguous load/lane, no staging. r10/r11 VALU convs were stuck at
//   ~55us (latency-bound, 0% MFMA, VGPR-alloc fights); MFMA floor ~0.6us.
//   Output via 16KB LDS transpose -> 4 coalesced uint4 stores/thread.
//   flash (qproj folded) and combine unchanged.
// ws layout:
//  WS_A:  Opart fp32 [64][128][256] = 8 MB  [0, 8388608)
//  WS_B:  K bf16 [4][4096][256]     = 8 MB  [8388608, 16777216)
//  WS_C:  V bf16 [4][4096][256]     = 8 MB  [16777216, 25165824)
//  WS_LP: lpart fp32 [64][128]      = 32KB  [25452544, 25485312)
#define WS_A      0u
#define WS_B      8388608u
#define WS_C      16777216u
#define WS_LP     25452544u
#define WS_NEEDED 25485312u

__device__ __forceinline__ u16 f2bf(float f){
  u32 u = __float_as_uint(f);
  return (u16)((u + 0x7fffu + ((u >> 16) & 1u)) >> 16);   // RNE
}

__global__ __launch_bounds__(256) void zero_out_kernel(float* __restrict__ out){
  int t = blockIdx.x * 256 + threadIdx.x;
  ((float4*)out)[t] = make_float4(0.f, 0.f, 0.f, 0.f);
}

// K0: Conv3d(32->64ch, k=(3,1,1), pad=(1,0,0)) as hi/lo-split bf16 MFMA GEMM.
// Grid 1024 = (b, x, wc, mhalf). Block: D[64 o][128 m], 4 waves = 4 o-tiles.
// Wave w4: o in [w4*16, w4*16+16), 8 m-tiles of 16. Per (dx, mt): one 32B
// contiguous load/lane (8 consecutive c), trunc hi/lo split, 3 MFMA.
// A-frags: W[o=w4*16+l15][c=quad*8+e][dx] gathered once (24 dwords/lane).
// OOB x-taps: skip dx (== fmaf(0,w,a) exactly).
// Epilogue: LDS [64 o][128 m] transpose -> 4 coalesced uint4 stores/thread.
__global__ __launch_bounds__(256, 4) void conv_kernel(const float* __restrict__ storage,
    const float* __restrict__ w_cross, const float* __restrict__ b_cross,
    u16* __restrict__ Kb, u16* __restrict__ Vb){
  int bid = blockIdx.x;
  int mhalf = bid & 1;
  int wc    = (bid >> 1) & 3;
  int x     = (bid >> 3) & 31;
  int b     = bid >> 8;
  int tid = threadIdx.x;
  int w4 = tid >> 6;
  int lane = tid & 63, l15 = lane & 15, quad = lane >> 4;

  // ---- A-frags: weights, trunc hi/lo split ----
  s16x8 Ahi[3], Alo[3];
  {
    int o = w4*16 + l15;
    #pragma unroll
    for (int dx = 0; dx < 3; ++dx){
      #pragma unroll
      for (int e = 0; e < 8; ++e){
        float wv = w_cross[o*96 + (quad*8 + e)*3 + dx];
        u32 u = __float_as_uint(wv);
        float r = wv - __uint_as_float(u & 0xffff0000u);
        Ahi[dx][e] = (short)(u >> 16);
        Alo[dx][e] = (short)(__float_as_uint(r) >> 16);
      }
    }
  }

  // ---- acc init with bias: D row = quad*4 + reg ----
  f32x4 acc[8];
  {
    float4 bv = *(const float4*)(b_cross + w4*16 + quad*4);
    #pragma unroll
    for (int mt = 0; mt < 8; ++mt) acc[mt] = (f32x4){bv.x, bv.y, bv.z, bv.w};
  }

  // ---- main: 3 dx-taps x 8 m-tiles, 3 MFMA each ----
  // mcol = mhalf*128 + mt*16 + l15; h = mcol&7 = l15&7; wl = mcol>>3.
  #pragma unroll
  for (int dx = 0; dx < 3; ++dx){
    int xx = x + dx - 1;
    if (xx < 0 || xx > 31) continue;   // block-uniform
    const float* pb = storage +
        ((((size_t)b*32 + xx)*8 + (l15 & 7))*128 + wc*32 + mhalf*16 + (l15 >> 3))*32 + quad*8;
    #pragma unroll
    for (int mt = 0; mt < 8; ++mt){
      float4 va  = *(const float4*)(pb + mt*64);
      float4 vb2 = *(const float4*)(pb + mt*64 + 4);
      float v[8] = {va.x, va.y, va.z, va.w, vb2.x, vb2.y, vb2.z, vb2.w};
      s16x8 bhi, blo;
      #pragma unroll
      for (int e = 0; e < 8; ++e){
        u32 u = __float_as_uint(v[e]);
        float r = v[e] - __uint_as_float(u & 0xffff0000u);
        bhi[e] = (short)(u >> 16);
        blo[e] = (short)(__float_as_uint(r) >> 16);
      }
      acc[mt] = __builtin_amdgcn_mfma_f32_16x16x32_bf16(Ahi[dx], bhi, acc[mt], 0, 0, 0);
      acc[mt] = __builtin_amdgcn_mfma_f32_16x16x32_bf16(Ahi[dx], blo, acc[mt], 0, 0, 0);
      acc[mt] = __builtin_amdgcn_mfma_f32_16x16x32_bf16(Alo[dx], bhi, acc[mt], 0, 0, 0);
    }
  }

  // ---- epilogue: LDS transpose -> coalesced stores ----
  __shared__ u16 st[64 * 128];
  #pragma unroll
  for (int mt = 0; mt < 8; ++mt){
    #pragma unroll
    for (int r = 0; r < 4; ++r)
      st[(w4*16 + quad*4 + r)*128 + mt*16 + l15] = f2bf(acc[mt][r]);
  }
  __syncthreads();
  int o = tid >> 2, part = tid & 3;
  int ck = o & 31;   // V: out-ch 0..31, K: 32..63
  size_t base = ((size_t)b*4096 + (size_t)ck*128 + (size_t)x*4 + wc)*256 + mhalf*128 + part*32;
  u16* dst = (o < 32 ? Vb : Kb) + base;
  const u16* src = &st[o*128 + part*32];
  *(uint4*)(dst)      = *(const uint4*)(src);
  *(uint4*)(dst + 8)  = *(const uint4*)(src + 8);
  *(uint4*)(dst + 16) = *(const uint4*)(src + 16);
  *(uint4*)(dst + 24) = *(const uint4*)(src + 24);
}

// K1: flash v2 + integrated qproj. Block = (b, kq: 16 x 256-key chunk,
// rb: 8 x 16-row). Grid 512. Prologue: each thread (wl,h) computes the 16
// Q values (cql x wcq) for its column m = wl*8+h — identical FMA order to
// the original prep kernel -> bit-identical bf16 Q. Staged in LDS (overlay
// on Vts, padded rows of 264 u16 so qa reads are 2-way/free), then qa frags.
// Main loop: no-max softmax, K direct-from-global, V^T LDS XOR-swizzled,
// kq-split sums.
__global__ __launch_bounds__(256, 2) void flash_kernel(const float* __restrict__ target,
    const float* __restrict__ w_q, const float* __restrict__ b_q,
    const u16* __restrict__ Kb, const u16* __restrict__ Vb,
    float* __restrict__ Opart, float* __restrict__ lpart){
  int kq = blockIdx.x & 15, rb = (blockIdx.x >> 4) & 7, b = blockIdx.x >> 7;
  int tid = threadIdx.x;
  int w = tid >> 6, lane = tid & 63, l15 = lane & 15, quad = lane >> 4;

  __shared__ alignas(16) u16 Vts[256 * 64];   // [m][64 keys] XOR-swizzled, 32KB
  __shared__ alignas(16) u16 Ps[16 * 64];     // [row][64 keys] XOR-swizzled, 2KB
  __shared__ float lsumW[64];                 // [wave][16 rows]

  // ---- integrated qproj: rows r_local = cql*4 + wcq (global cq = rb*4+cql) ----
  u16* stgQ = Vts;   // overlay: 16 rows x 264 u16 = 8448 B
  {
    int wl = tid & 31, h = tid >> 5;
    #pragma unroll
    for (int wcq = 0; wcq < 4; ++wcq){
      float in[32];
      const float4* p = (const float4*)(target + (((size_t)b*8 + h)*128 + wcq*32 + wl)*32);
      #pragma unroll
      for (int q = 0; q < 8; ++q){
        float4 v = p[q];
        in[q*4+0] = v.x; in[q*4+1] = v.y; in[q*4+2] = v.z; in[q*4+3] = v.w;
      }
      #pragma unroll
      for (int cql = 0; cql < 4; ++cql){
        int cq = rb*4 + cql;                       // block-uniform
        float acc = b_q[cq];
        #pragma unroll
        for (int c = 0; c < 32; ++c) acc = fmaf(in[c], w_q[cq*32 + c], acc);
        stgQ[(cql*4 + wcq)*264 + wl*8 + h] = f2bf(acc);
      }
    }
  }
  __syncthreads();

  // persistent Q A-frags: local rows l15, k = ks*32 + quad*8
  s16x8 qa[8];
  {
    const u16* qp = stgQ + l15*264 + quad*8;
    #pragma unroll
    for (int ks = 0; ks < 8; ++ks) qa[ks] = *(const s16x8*)(qp + ks*32);
  }
  __syncthreads();   // all qa reads done before Vts is reused

  int jl4 = tid & 15, mseg = tid >> 4;   // V staging: keys jl4*4..+3, m mseg*16..+15
  const u16* kbase = Kb + ((size_t)(b*4096 + kq*256 + w*16 + l15))*256 + quad*8;
  const u16* vbase = Vb + ((size_t)(b*4096 + kq*256 + jl4*4))*256 + mseg*16;

  // prefetch tile 0
  s16x8 kr[8];
  #pragma unroll
  for (int ks = 0; ks < 8; ++ks) kr[ks] = *(const s16x8*)(kbase + ks*32);
  u32 kv[4][8];
  #pragma unroll
  for (int kk = 0; kk < 4; ++kk){
    uint4 a = *(const uint4*)(vbase + kk*256);
    uint4 b2 = *(const uint4*)(vbase + kk*256 + 8);
    kv[kk][0]=a.x; kv[kk][1]=a.y; kv[kk][2]=a.z; kv[kk][3]=a.w;
    kv[kk][4]=b2.x; kv[kk][5]=b2.y; kv[kk][6]=b2.z; kv[kk][7]=b2.w;
  }

  float lacc[4] = {0.f, 0.f, 0.f, 0.f};
  f32x4 oc[4];
  #pragma unroll
  for (int mt = 0; mt < 4; ++mt) oc[mt] = (f32x4){0.f,0.f,0.f,0.f};

  #pragma unroll
  for (int it = 0; it < 4; ++it){
    if (it > 0) __syncthreads();   // prev PV done reading Vts/Ps

    // ---- phase 1: V^T -> LDS (b64 transposed, swizzled) ----
    #pragma unroll
    for (int i = 0; i < 16; ++i){
      int d = i >> 1;
      u32 e0, e1, e2, e3;
      if (i & 1){ e0 = kv[0][d] >> 16;     e1 = kv[1][d] >> 16;
                  e2 = kv[2][d] >> 16;     e3 = kv[3][d] >> 16; }
      else      { e0 = kv[0][d] & 0xffffu; e1 = kv[1][d] & 0xffffu;
                  e2 = kv[2][d] & 0xffffu; e3 = kv[3][d] & 0xffffu; }
      int m = mseg*16 + i;
      int col = (((jl4 >> 1) ^ (m & 7)) << 3) + ((jl4 & 1) << 2);
      *(uint2*)&Vts[m*64 + col] = make_uint2(e0 | (e1 << 16), e2 | (e3 << 16));
    }

    // ---- scores: D[row=quad*4+reg][key=w*16+l15], K frags from regs ----
    f32x4 s0 = {0.f,0.f,0.f,0.f}, s1 = {0.f,0.f,0.f,0.f};
    #pragma unroll
    for (int ks = 0; ks < 8; ks += 2){
      s0 = __builtin_amdgcn_mfma_f32_16x16x32_bf16(qa[ks],   kr[ks],   s0, 0, 0, 0);
      s1 = __builtin_amdgcn_mfma_f32_16x16x32_bf16(qa[ks+1], kr[ks+1], s1, 0, 0, 0);
    }
    int b8k = w*2 + (l15 >> 3);
    #pragma unroll
    for (int reg = 0; reg < 4; ++reg){
      float sv = fminf(s0[reg] + s1[reg], 80.f);
      float p = __expf(sv);
      int row = quad*4 + reg;
      Ps[row*64 + ((b8k ^ (row & 7)) << 3) + (l15 & 7)] = f2bf(p);
      lacc[reg] += p;
    }

    // prefetch V(t+1)
    if (it < 3){
      const u16* vp = vbase + (it+1)*16384;
      #pragma unroll
      for (int kk = 0; kk < 4; ++kk){
        uint4 a = *(const uint4*)(vp + kk*256);
        uint4 b2 = *(const uint4*)(vp + kk*256 + 8);
        kv[kk][0]=a.x; kv[kk][1]=a.y; kv[kk][2]=a.z; kv[kk][3]=a.w;
        kv[kk][4]=b2.x; kv[kk][5]=b2.y; kv[kk][6]=b2.z; kv[kk][7]=b2.w;
      }
    }
    __syncthreads();

    // ---- phase 2: PV. prefetch K(t+1) first (covered by MFMAs) ----
    if (it < 3){
      const u16* kp = kbase + (it+1)*16384;
      #pragma unroll
      for (int ks = 0; ks < 8; ++ks) kr[ks] = *(const s16x8*)(kp + ks*32);
    }
    #pragma unroll
    for (int ks2 = 0; ks2 < 2; ++ks2){
      int b8 = ks2*4 + quad;
      s16x8 pb = *(const s16x8*)&Ps[l15*64 + ((b8 ^ (l15 & 7)) << 3)];
      #pragma unroll
      for (int mt = 0; mt < 4; ++mt){
        int mrow = (w*4 + mt)*16 + l15;
        s16x8 af = *(const s16x8*)&Vts[mrow*64 + ((b8 ^ (mrow & 7)) << 3)];
        oc[mt] = __builtin_amdgcn_mfma_f32_16x16x32_bf16(af, pb, oc[mt], 0, 0, 0);
      }
    }
  }

  // ---- epilogue ----
  #pragma unroll
  for (int reg = 0; reg < 4; ++reg){
    float t = lacc[reg];
    t += __shfl_xor(t, 1); t += __shfl_xor(t, 2);
    t += __shfl_xor(t, 4); t += __shfl_xor(t, 8);
    lacc[reg] = t;
  }
  if (l15 == 0){
    #pragma unroll
    for (int reg = 0; reg < 4; ++reg) lsumW[w*16 + quad*4 + reg] = lacc[reg];
  }
  __syncthreads();
  if (tid < 16)
    lpart[(b*16 + kq)*128 + rb*16 + tid] =
        lsumW[tid] + lsumW[16 + tid] + lsumW[32 + tid] + lsumW[48 + tid];
  // O: lane holds rows l15, m = w*64 + mt*16 + quad*4 + reg
  {
    float* dst = Opart + ((size_t)((b*16 + kq)*128 + rb*16 + l15))*256 + w*64 + quad*4;
    #pragma unroll
    for (int mt = 0; mt < 4; ++mt)
      *(float4*)(dst + mt*16) = make_float4(oc[mt][0], oc[mt][1], oc[mt][2], oc[mt][3]);
  }
}

// K2: combine 16 kq-partials (plain sums — softmax un-normalized), divide,
// broadcast-scatter (row r=(cq,whi) -> 32 slots, contiguous 256-float stores).
__global__ __launch_bounds__(256) void combine_kernel(const float* __restrict__ lpart,
    const float* __restrict__ Opart, float* __restrict__ out){
  int r = blockIdx.x & 127, b = blockIdx.x >> 7;
  int m = threadIdx.x;
  float L = 0.f, o = 0.f;
  #pragma unroll
  for (int kq = 0; kq < 16; ++kq){
    L += lpart[(b*16 + kq)*128 + r];
    o += Opart[((size_t)((b*16 + kq)*128 + r))*256 + m];
  }
  o /= L;
  int cq = r >> 2, whi = r & 3;
  size_t obase = ((size_t)b*32 + cq) * 32768;
  #pragma unroll
  for (int hh = 0; hh < 8; ++hh){
    #pragma unroll
    for (int wt = 0; wt < 4; ++wt){
      out[obase + hh*4096 + wt*1024 + whi*256 + m] = o;
    }
  }
}

extern "C" void kernel_launch(void* const* d_in, const int* in_sizes, int n_in,
                              void* d_out, int out_size, void* d_ws, size_t ws_size,
                              hipStream_t stream){
  const float* storage = (const float*)d_in[0];
  const float* target  = (const float*)d_in[1];
  const float* w_cross = (const float*)d_in[2];
  const float* b_cross = (const float*)d_in[3];
  const float* w_q     = (const float*)d_in[4];
  const float* b_q     = (const float*)d_in[5];
  float* out = (float*)d_out;

  if (ws_size < (size_t)WS_NEEDED){
    zero_out_kernel<<<dim3(4096), dim3(256), 0, stream>>>(out);
    return;
  }

  char* ws = (char*)d_ws;
  float* Opart = (float*)(ws + WS_A);
  u16*   Kb    = (u16*)(ws + WS_B);
  u16*   Vb    = (u16*)(ws + WS_C);
  float* lpart = (float*)(ws + WS_LP);

  conv_kernel    <<<dim3(1024), dim3(256), 0, stream>>>(storage, w_cross, b_cross, Kb, Vb);
  flash_kernel   <<<dim3(512),  dim3(256), 0, stream>>>(target, w_q, b_q, Kb, Vb, Opart, lpart);
  combine_kernel <<<dim3(512),  dim3(256), 0, stream>>>(lpart, Opart, out);
}

// Round 4
// 141.840 us; speedup vs baseline: 1.1204x; 1.0112x over previous
//
#include <hip/hip_runtime.h>

typedef unsigned short u16;
typedef unsigned int u32;
typedef __attribute__((ext_vector_type(8))) short s16x8;   // 8 bf16 (4 VGPR) MFMA A/B frag
typedef __attribute__((ext_vector_type(4))) float f32x4;   // MFMA C/D frag

// Problem dims: B=4, X=32, H=8, W=128, C=32 (all fp32 in/out)
// Attention view: 4096 keys, M=256 cols, 128 distinct query rows per batch.
//
// r13: conv A-frag weight load fixed. r12 gathered 24 scattered 4B loads
//   per thread (64 distinct cachelines per wave instruction -> ~1 line/cyc
//   L1 service ~ 10+us serialized). Each lane actually needs 24 CONSECUTIVE
//   floats (w_cross[o*96 + quad*24 ..+24) covers all (e,dx): j=e*3+dx), so
//   load 6 coalesced float4 and split from registers. Bit-identical math.
//   Everything else unchanged from r12.
// ws layout:
//  WS_A:  Opart fp32 [64][128][256] = 8 MB  [0, 8388608)
//  WS_B:  K bf16 [4][4096][256]     = 8 MB  [8388608, 16777216)
//  WS_C:  V bf16 [4][4096][256]     = 8 MB  [16777216, 25165824)
//  WS_LP: lpart fp32 [64][128]      = 32KB  [25452544, 25485312)
#define WS_A      0u
#define WS_B      8388608u
#define WS_C      16777216u
#define WS_LP     25452544u
#define WS_NEEDED 25485312u

__device__ __forceinline__ u16 f2bf(float f){
  u32 u = __float_as_uint(f);
  return (u16)((u + 0x7fffu + ((u >> 16) & 1u)) >> 16);   // RNE
}

__global__ __launch_bounds__(256) void zero_out_kernel(float* __restrict__ out){
  int t = blockIdx.x * 256 + threadIdx.x;
  ((float4*)out)[t] = make_float4(0.f, 0.f, 0.f, 0.f);
}

// K0: Conv3d(32->64ch, k=(3,1,1), pad=(1,0,0)) as hi/lo-split bf16 MFMA GEMM.
// Grid 1024 = (b, x, wc, mhalf). Block: D[64 o][128 m], 4 waves = 4 o-tiles.
// Wave w4: o in [w4*16, w4*16+16), 8 m-tiles of 16. Per (dx, mt): one 32B
// contiguous load/lane (8 consecutive c), trunc hi/lo split, 3 MFMA
// (hihi + hilo + lohi; lo.lo ~2^-14 skipped).
// A-frags: lane loads w_cross[o*96 + quad*24 ..+24) = 6 coalesced float4
// (dense 24KB sweep per wave), split in-register; w24[e*3+dx] = W[o][c][dx].
// OOB x-taps: skip dx (== fmaf(0,w,a) exactly).
// Epilogue: LDS [64 o][128 m] transpose -> 4 coalesced uint4 stores/thread.
__global__ __launch_bounds__(256, 4) void conv_kernel(const float* __restrict__ storage,
    const float* __restrict__ w_cross, const float* __restrict__ b_cross,
    u16* __restrict__ Kb, u16* __restrict__ Vb){
  int bid = blockIdx.x;
  int mhalf = bid & 1;
  int wc    = (bid >> 1) & 3;
  int x     = (bid >> 3) & 31;
  int b     = bid >> 8;
  int tid = threadIdx.x;
  int w4 = tid >> 6;
  int lane = tid & 63, l15 = lane & 15, quad = lane >> 4;

  // ---- A-frags: 6 coalesced float4 loads, then trunc hi/lo split ----
  s16x8 Ahi[3], Alo[3];
  {
    int o = w4*16 + l15;
    const float4* wp = (const float4*)(w_cross + o*96 + quad*24);
    float w24[24];
    #pragma unroll
    for (int i = 0; i < 6; ++i){
      float4 v = wp[i];
      w24[i*4+0] = v.x; w24[i*4+1] = v.y; w24[i*4+2] = v.z; w24[i*4+3] = v.w;
    }
    #pragma unroll
    for (int dx = 0; dx < 3; ++dx){
      #pragma unroll
      for (int e = 0; e < 8; ++e){
        float wv = w24[e*3 + dx];
        u32 u = __float_as_uint(wv);
        float r = wv - __uint_as_float(u & 0xffff0000u);
        Ahi[dx][e] = (short)(u >> 16);
        Alo[dx][e] = (short)(__float_as_uint(r) >> 16);
      }
    }
  }

  // ---- acc init with bias: D row = quad*4 + reg ----
  f32x4 acc[8];
  {
    float4 bv = *(const float4*)(b_cross + w4*16 + quad*4);
    #pragma unroll
    for (int mt = 0; mt < 8; ++mt) acc[mt] = (f32x4){bv.x, bv.y, bv.z, bv.w};
  }

  // ---- main: 3 dx-taps x 8 m-tiles, 3 MFMA each ----
  // mcol = mhalf*128 + mt*16 + l15; h = mcol&7 = l15&7; wl = mcol>>3.
  #pragma unroll
  for (int dx = 0; dx < 3; ++dx){
    int xx = x + dx - 1;
    if (xx < 0 || xx > 31) continue;   // block-uniform
    const float* pb = storage +
        ((((size_t)b*32 + xx)*8 + (l15 & 7))*128 + wc*32 + mhalf*16 + (l15 >> 3))*32 + quad*8;
    #pragma unroll
    for (int mt = 0; mt < 8; ++mt){
      float4 va  = *(const float4*)(pb + mt*64);
      float4 vb2 = *(const float4*)(pb + mt*64 + 4);
      float v[8] = {va.x, va.y, va.z, va.w, vb2.x, vb2.y, vb2.z, vb2.w};
      s16x8 bhi, blo;
      #pragma unroll
      for (int e = 0; e < 8; ++e){
        u32 u = __float_as_uint(v[e]);
        float r = v[e] - __uint_as_float(u & 0xffff0000u);
        bhi[e] = (short)(u >> 16);
        blo[e] = (short)(__float_as_uint(r) >> 16);
      }
      acc[mt] = __builtin_amdgcn_mfma_f32_16x16x32_bf16(Ahi[dx], bhi, acc[mt], 0, 0, 0);
      acc[mt] = __builtin_amdgcn_mfma_f32_16x16x32_bf16(Ahi[dx], blo, acc[mt], 0, 0, 0);
      acc[mt] = __builtin_amdgcn_mfma_f32_16x16x32_bf16(Alo[dx], bhi, acc[mt], 0, 0, 0);
    }
  }

  // ---- epilogue: LDS transpose -> coalesced stores ----
  __shared__ u16 st[64 * 128];
  #pragma unroll
  for (int mt = 0; mt < 8; ++mt){
    #pragma unroll
    for (int r = 0; r < 4; ++r)
      st[(w4*16 + quad*4 + r)*128 + mt*16 + l15] = f2bf(acc[mt][r]);
  }
  __syncthreads();
  int o = tid >> 2, part = tid & 3;
  int ck = o & 31;   // V: out-ch 0..31, K: 32..63
  size_t base = ((size_t)b*4096 + (size_t)ck*128 + (size_t)x*4 + wc)*256 + mhalf*128 + part*32;
  u16* dst = (o < 32 ? Vb : Kb) + base;
  const u16* src = &st[o*128 + part*32];
  *(uint4*)(dst)      = *(const uint4*)(src);
  *(uint4*)(dst + 8)  = *(const uint4*)(src + 8);
  *(uint4*)(dst + 16) = *(const uint4*)(src + 16);
  *(uint4*)(dst + 24) = *(const uint4*)(src + 24);
}

// K1: flash v2 + integrated qproj. Block = (b, kq: 16 x 256-key chunk,
// rb: 8 x 16-row). Grid 512. Prologue: each thread (wl,h) computes the 16
// Q values (cql x wcq) for its column m = wl*8+h — identical FMA order to
// the original prep kernel -> bit-identical bf16 Q. Staged in LDS (overlay
// on Vts, padded rows of 264 u16 so qa reads are 2-way/free), then qa frags.
// Main loop: no-max softmax, K direct-from-global, V^T LDS XOR-swizzled,
// kq-split sums.
__global__ __launch_bounds__(256, 2) void flash_kernel(const float* __restrict__ target,
    const float* __restrict__ w_q, const float* __restrict__ b_q,
    const u16* __restrict__ Kb, const u16* __restrict__ Vb,
    float* __restrict__ Opart, float* __restrict__ lpart){
  int kq = blockIdx.x & 15, rb = (blockIdx.x >> 4) & 7, b = blockIdx.x >> 7;
  int tid = threadIdx.x;
  int w = tid >> 6, lane = tid & 63, l15 = lane & 15, quad = lane >> 4;

  __shared__ alignas(16) u16 Vts[256 * 64];   // [m][64 keys] XOR-swizzled, 32KB
  __shared__ alignas(16) u16 Ps[16 * 64];     // [row][64 keys] XOR-swizzled, 2KB
  __shared__ float lsumW[64];                 // [wave][16 rows]

  // ---- integrated qproj: rows r_local = cql*4 + wcq (global cq = rb*4+cql) ----
  u16* stgQ = Vts;   // overlay: 16 rows x 264 u16 = 8448 B
  {
    int wl = tid & 31, h = tid >> 5;
    #pragma unroll
    for (int wcq = 0; wcq < 4; ++wcq){
      float in[32];
      const float4* p = (const float4*)(target + (((size_t)b*8 + h)*128 + wcq*32 + wl)*32);
      #pragma unroll
      for (int q = 0; q < 8; ++q){
        float4 v = p[q];
        in[q*4+0] = v.x; in[q*4+1] = v.y; in[q*4+2] = v.z; in[q*4+3] = v.w;
      }
      #pragma unroll
      for (int cql = 0; cql < 4; ++cql){
        int cq = rb*4 + cql;                       // block-uniform
        float acc = b_q[cq];
        #pragma unroll
        for (int c = 0; c < 32; ++c) acc = fmaf(in[c], w_q[cq*32 + c], acc);
        stgQ[(cql*4 + wcq)*264 + wl*8 + h] = f2bf(acc);
      }
    }
  }
  __syncthreads();

  // persistent Q A-frags: local rows l15, k = ks*32 + quad*8
  s16x8 qa[8];
  {
    const u16* qp = stgQ + l15*264 + quad*8;
    #pragma unroll
    for (int ks = 0; ks < 8; ++ks) qa[ks] = *(const s16x8*)(qp + ks*32);
  }
  __syncthreads();   // all qa reads done before Vts is reused

  int jl4 = tid & 15, mseg = tid >> 4;   // V staging: keys jl4*4..+3, m mseg*16..+15
  const u16* kbase = Kb + ((size_t)(b*4096 + kq*256 + w*16 + l15))*256 + quad*8;
  const u16* vbase = Vb + ((size_t)(b*4096 + kq*256 + jl4*4))*256 + mseg*16;

  // prefetch tile 0
  s16x8 kr[8];
  #pragma unroll
  for (int ks = 0; ks < 8; ++ks) kr[ks] = *(const s16x8*)(kbase + ks*32);
  u32 kv[4][8];
  #pragma unroll
  for (int kk = 0; kk < 4; ++kk){
    uint4 a = *(const uint4*)(vbase + kk*256);
    uint4 b2 = *(const uint4*)(vbase + kk*256 + 8);
    kv[kk][0]=a.x; kv[kk][1]=a.y; kv[kk][2]=a.z; kv[kk][3]=a.w;
    kv[kk][4]=b2.x; kv[kk][5]=b2.y; kv[kk][6]=b2.z; kv[kk][7]=b2.w;
  }

  float lacc[4] = {0.f, 0.f, 0.f, 0.f};
  f32x4 oc[4];
  #pragma unroll
  for (int mt = 0; mt < 4; ++mt) oc[mt] = (f32x4){0.f,0.f,0.f,0.f};

  #pragma unroll
  for (int it = 0; it < 4; ++it){
    if (it > 0) __syncthreads();   // prev PV done reading Vts/Ps

    // ---- phase 1: V^T -> LDS (b64 transposed, swizzled) ----
    #pragma unroll
    for (int i = 0; i < 16; ++i){
      int d = i >> 1;
      u32 e0, e1, e2, e3;
      if (i & 1){ e0 = kv[0][d] >> 16;     e1 = kv[1][d] >> 16;
                  e2 = kv[2][d] >> 16;     e3 = kv[3][d] >> 16; }
      else      { e0 = kv[0][d] & 0xffffu; e1 = kv[1][d] & 0xffffu;
                  e2 = kv[2][d] & 0xffffu; e3 = kv[3][d] & 0xffffu; }
      int m = mseg*16 + i;
      int col = (((jl4 >> 1) ^ (m & 7)) << 3) + ((jl4 & 1) << 2);
      *(uint2*)&Vts[m*64 + col] = make_uint2(e0 | (e1 << 16), e2 | (e3 << 16));
    }

    // ---- scores: D[row=quad*4+reg][key=w*16+l15], K frags from regs ----
    f32x4 s0 = {0.f,0.f,0.f,0.f}, s1 = {0.f,0.f,0.f,0.f};
    #pragma unroll
    for (int ks = 0; ks < 8; ks += 2){
      s0 = __builtin_amdgcn_mfma_f32_16x16x32_bf16(qa[ks],   kr[ks],   s0, 0, 0, 0);
      s1 = __builtin_amdgcn_mfma_f32_16x16x32_bf16(qa[ks+1], kr[ks+1], s1, 0, 0, 0);
    }
    int b8k = w*2 + (l15 >> 3);
    #pragma unroll
    for (int reg = 0; reg < 4; ++reg){
      float sv = fminf(s0[reg] + s1[reg], 80.f);
      float p = __expf(sv);
      int row = quad*4 + reg;
      Ps[row*64 + ((b8k ^ (row & 7)) << 3) + (l15 & 7)] = f2bf(p);
      lacc[reg] += p;
    }

    // prefetch V(t+1)
    if (it < 3){
      const u16* vp = vbase + (it+1)*16384;
      #pragma unroll
      for (int kk = 0; kk < 4; ++kk){
        uint4 a = *(const uint4*)(vp + kk*256);
        uint4 b2 = *(const uint4*)(vp + kk*256 + 8);
        kv[kk][0]=a.x; kv[kk][1]=a.y; kv[kk][2]=a.z; kv[kk][3]=a.w;
        kv[kk][4]=b2.x; kv[kk][5]=b2.y; kv[kk][6]=b2.z; kv[kk][7]=b2.w;
      }
    }
    __syncthreads();

    // ---- phase 2: PV. prefetch K(t+1) first (covered by MFMAs) ----
    if (it < 3){
      const u16* kp = kbase + (it+1)*16384;
      #pragma unroll
      for (int ks = 0; ks < 8; ++ks) kr[ks] = *(const s16x8*)(kp + ks*32);
    }
    #pragma unroll
    for (int ks2 = 0; ks2 < 2; ++ks2){
      int b8 = ks2*4 + quad;
      s16x8 pb = *(const s16x8*)&Ps[l15*64 + ((b8 ^ (l15 & 7)) << 3)];
      #pragma unroll
      for (int mt = 0; mt < 4; ++mt){
        int mrow = (w*4 + mt)*16 + l15;
        s16x8 af = *(const s16x8*)&Vts[mrow*64 + ((b8 ^ (mrow & 7)) << 3)];
        oc[mt] = __builtin_amdgcn_mfma_f32_16x16x32_bf16(af, pb, oc[mt], 0, 0, 0);
      }
    }
  }

  // ---- epilogue ----
  #pragma unroll
  for (int reg = 0; reg < 4; ++reg){
    float t = lacc[reg];
    t += __shfl_xor(t, 1); t += __shfl_xor(t, 2);
    t += __shfl_xor(t, 4); t += __shfl_xor(t, 8);
    lacc[reg] = t;
  }
  if (l15 == 0){
    #pragma unroll
    for (int reg = 0; reg < 4; ++reg) lsumW[w*16 + quad*4 + reg] = lacc[reg];
  }
  __syncthreads();
  if (tid < 16)
    lpart[(b*16 + kq)*128 + rb*16 + tid] =
        lsumW[tid] + lsumW[16 + tid] + lsumW[32 + tid] + lsumW[48 + tid];
  // O: lane holds rows l15, m = w*64 + mt*16 + quad*4 + reg
  {
    float* dst = Opart + ((size_t)((b*16 + kq)*128 + rb*16 + l15))*256 + w*64 + quad*4;
    #pragma unroll
    for (int mt = 0; mt < 4; ++mt)
      *(float4*)(dst + mt*16) = make_float4(oc[mt][0], oc[mt][1], oc[mt][2], oc[mt][3]);
  }
}

// K2: combine 16 kq-partials (plain sums — softmax un-normalized), divide,
// broadcast-scatter (row r=(cq,whi) -> 32 slots, contiguous 256-float stores).
__global__ __launch_bounds__(256) void combine_kernel(const float* __restrict__ lpart,
    const float* __restrict__ Opart, float* __restrict__ out){
  int r = blockIdx.x & 127, b = blockIdx.x >> 7;
  int m = threadIdx.x;
  float L = 0.f, o = 0.f;
  #pragma unroll
  for (int kq = 0; kq < 16; ++kq){
    L += lpart[(b*16 + kq)*128 + r];
    o += Opart[((size_t)((b*16 + kq)*128 + r))*256 + m];
  }
  o /= L;
  int cq = r >> 2, whi = r & 3;
  size_t obase = ((size_t)b*32 + cq) * 32768;
  #pragma unroll
  for (int hh = 0; hh < 8; ++hh){
    #pragma unroll
    for (int wt = 0; wt < 4; ++wt){
      out[obase + hh*4096 + wt*1024 + whi*256 + m] = o;
    }
  }
}

extern "C" void kernel_launch(void* const* d_in, const int* in_sizes, int n_in,
                              void* d_out, int out_size, void* d_ws, size_t ws_size,
                              hipStream_t stream){
  const float* storage = (const float*)d_in[0];
  const float* target  = (const float*)d_in[1];
  const float* w_cross = (const float*)d_in[2];
  const float* b_cross = (const float*)d_in[3];
  const float* w_q     = (const float*)d_in[4];
  const float* b_q     = (const float*)d_in[5];
  float* out = (float*)d_out;

  if (ws_size < (size_t)WS_NEEDED){
    zero_out_kernel<<<dim3(4096), dim3(256), 0, stream>>>(out);
    return;
  }

  char* ws = (char*)d_ws;
  float* Opart = (float*)(ws + WS_A);
  u16*   Kb    = (u16*)(ws + WS_B);
  u16*   Vb    = (u16*)(ws + WS_C);
  float* lpart = (float*)(ws + WS_LP);

  conv_kernel    <<<dim3(1024), dim3(256), 0, stream>>>(storage, w_cross, b_cross, Kb, Vb);
  flash_kernel   <<<dim3(512),  dim3(256), 0, stream>>>(target, w_q, b_q, Kb, Vb, Opart, lpart);
  combine_kernel <<<dim3(512),  dim3(256), 0, stream>>>(lpart, Opart, out);
}